// Round 6
// baseline (20838.362 us; speedup 1.0000x reference)
//
#include <hip/hip_runtime.h>
#include <cmath>

// n = m = 8192, d = 64, reg = 0.05, 20 Sinkhorn iterations
#define NPTS 8192
#define DIM  64
#define LOG2E 1.4426950408889634f
#define LA2   -13.0f   // log2(1/8192) exactly

typedef short s16x8  __attribute__((ext_vector_type(8)));   // 8 bf16
typedef float f32x16 __attribute__((ext_vector_type(16)));  // MFMA 32x32 acc

typedef __attribute__((address_space(1))) const unsigned char g8_t;
typedef __attribute__((address_space(3))) unsigned char l8_t;

#if __has_builtin(__builtin_amdgcn_exp2f)
__device__ __forceinline__ float exp2_fast(float x) { return __builtin_amdgcn_exp2f(x); }
#else
__device__ __forceinline__ float exp2_fast(float x) { return exp2f(x); }
#endif
#if __has_builtin(__builtin_amdgcn_logf)
__device__ __forceinline__ float log2_fast(float x) { return __builtin_amdgcn_logf(x); }
#else
__device__ __forceinline__ float log2_fast(float x) { return log2f(x); }
#endif

__device__ __forceinline__ unsigned short f2bf(float x) {
  unsigned u = __float_as_uint(x);
  return (unsigned short)((u + 0x7FFFu + ((u >> 16) & 1u)) >> 16);
}
__device__ __forceinline__ float bf2f(unsigned short b) {
  return __uint_as_float(((unsigned)b) << 16);
}

// ---------------------------------------------------------------------------
// prep: bf16 hi/lo split + squared row norms; init scal/out. one wave per row.
// ---------------------------------------------------------------------------
__global__ __launch_bounds__(256) void prep_kernel(
    const float* __restrict__ XP, const float* __restrict__ XQ,
    unsigned short* __restrict__ Phi, unsigned short* __restrict__ Plo,
    unsigned short* __restrict__ Qhi, unsigned short* __restrict__ Qlo,
    float* __restrict__ x2, float* __restrict__ y2,
    float* __restrict__ scal, float* __restrict__ out) {
  int gid  = blockIdx.x * 256 + threadIdx.x;
  int lane = threadIdx.x & 63;
  int row  = gid >> 6;            // 0..16383: P rows then Q rows (wave-uniform)
  int isP  = row < NPTS;
  int r    = row & (NPTS - 1);
  const float* X = isP ? XP : XQ;
  float x = X[r * DIM + lane];
  unsigned short h = f2bf(x);
  (isP ? Phi : Qhi)[r * DIM + lane] = h;
  (isP ? Plo : Qlo)[r * DIM + lane] = f2bf(x - bf2f(h));
  float s = x * x;
  for (int off = 32; off; off >>= 1) s += __shfl_down(s, off, 64);
  if (lane == 0) (isP ? x2 : y2)[r] = s;
  if (gid == 0) { ((unsigned*)scal)[0] = 0u; out[0] = 0.0f; }
}

// ---------------------------------------------------------------------------
// pass_kernel<MODE, FIRST, MINW>: one (128 rows x 512 cols) tile sweep.
// Verified r2 structure (820 us): B staged as FOUR 16 KB quarters via
// global_load_lds, double-buffered in sB[2], 3 mid-sweep barriers.
// Round-6 change (MODE 1 only): ct steps processed as INTERLEAVED PAIRS with
// dual accumulators -- two independent MFMA chains issued alternately, then
// the two exp2 blocks in ct order. Breaks the serial
// ds_read -> chained-MFMA -> VALU dependency per wave (the r5 post-mortem
// stall theory: ~12 us/sweep of chain-latency exposure at 4 waves/SIMD).
// Accumulation order per racc[r] is unchanged (e(ct0) added before e(ct1)),
// so results are bitwise identical to r2. Modes 0/2 keep the verified body.
// MODE 0: cmax = max d2 (hi dot)                 -> atomicMax(uint) outScalar
// MODE 1: row sums of 2^(C2L*dot + b_j)          -> plain store outPart[gy][i]
// MODE 2: out += d2 * 2^(C2L*dot + bu_i + bv_j)  -> atomicAdd outScalar
// C/D layout (m74/m101): col = lane&31, row = (reg&3) + 8*(reg>>2) + 4*(lane>>5)
// ---------------------------------------------------------------------------
template <int MODE, bool FIRST, int MINW>
__global__ __launch_bounds__(256, MINW) void pass_kernel(
    const unsigned short* __restrict__ Ahi, const unsigned short* __restrict__ Alo,
    const unsigned short* __restrict__ Bhi,
    const float* __restrict__ x2row, const float* __restrict__ y2col,
    const float* __restrict__ colPart, const float* __restrict__ rowPart,
    const unsigned* __restrict__ cmaxBits,
    float* __restrict__ outPart, float* __restrict__ outScalar) {
  __shared__ short sB[2][128 * DIM];   // 2 x 16 KB quarter buffers, xor-swizzled
  __shared__ float sCol[512];          // per-col log2-domain base (modes 1,2)
  __shared__ float sY2[512];           // modes 0,2
  __shared__ float sX2[128];           // modes 0,2
  __shared__ float sU2[128];           // mode 2
  __shared__ float sRed[4];

  const int t  = threadIdx.x;
  const int w  = t >> 6;
  const int l  = t & 63;
  const int g  = l >> 5;
  const int ln = l & 31;
  const int i0 = blockIdx.x * 128;
  const int j0 = blockIdx.y * 512;

  float invC = 0.f, C2L = 0.f;
  if constexpr (MODE != 0) {
    float cmax = __uint_as_float(*cmaxBits);
    invC = 1.0f / (0.05f * cmax);
    C2L  = 2.0f * invC * LOG2E;
  }

  // staging geometry (verified r1/r2): slot s = w*256 + c*64 + l holds
  // (row = s>>3, chunk cc = (s&7)^(row&7)); row&7 == l>>3 -> cc c-invariant.
  const int gOff   = (w * 32 + (l >> 3)) * 128 + (((l & 7) ^ (l >> 3)) * 16);
  const int ldsOff = w * 4096 + l * 16;
  auto stage = [&](int qq, int bi) {
    const unsigned char* src =
        (const unsigned char*)(Bhi + (size_t)(j0 + qq * 128) * DIM) + gOff;
    unsigned char* dst = (unsigned char*)(&sB[bi][0]) + ldsOff;
#pragma unroll
    for (int c = 0; c < 4; ++c)
      __builtin_amdgcn_global_load_lds((g8_t*)(src + c * 1024),
                                       (l8_t*)(dst + c * 1024), 16, 0, 0);
  };

  stage(0, 0);
  stage(1, 1);

  // A fragments: lane holds A[m=ln][k = ks*16 + g*8 + j]
  s16x8 a_hi[4], a_lo[4];
  {
    const unsigned short* pa = Ahi + (size_t)(i0 + w * 32 + ln) * DIM + g * 8;
#pragma unroll
    for (int ks = 0; ks < 4; ++ks) a_hi[ks] = *(const s16x8*)(pa + ks * 16);
    if constexpr (MODE == 2) {
      const unsigned short* pb = Alo + (size_t)(i0 + w * 32 + ln) * DIM + g * 8;
#pragma unroll
      for (int ks = 0; ks < 4; ++ks) a_lo[ks] = *(const s16x8*)(pb + ks * 16);
    }
  }

  // whole-panel column bases / norms (overlaps the in-flight staging)
#pragma unroll
  for (int c0 = 0; c0 < 2; ++c0) {
    int c = c0 * 256 + t;
    int j = j0 + c;
    if constexpr (MODE == 0) {
      sY2[c] = y2col[j];
    } else if constexpr (MODE == 1) {
      if constexpr (FIRST) {
        sCol[c] = -invC * y2col[j] * LOG2E;
      } else {
        float s = 0.f;
#pragma unroll
        for (int gy = 0; gy < 16; ++gy) s += colPart[gy * NPTS + j];
        sCol[c] = LA2 - log2_fast(s);
      }
    } else {
      float s = 0.f;
#pragma unroll
      for (int gy = 0; gy < 16; ++gy) s += colPart[gy * NPTS + j];
      sCol[c] = LA2 - log2_fast(s);
      sY2[c] = y2col[j];
    }
  }
  if constexpr (MODE != 1) {
    if (t < 128) {
      sX2[t] = x2row[i0 + t];
      if constexpr (MODE == 2) {
        float s = 0.f;
#pragma unroll
        for (int gy = 0; gy < 16; ++gy) s += rowPart[gy * NPTS + i0 + t];
        sU2[t] = LA2 - log2_fast(s);
      }
    }
  }
  __syncthreads();   // drains quarters 0+1 (vmcnt at barrier), publishes sCol/...

  float x2r[16], u2r[16];
  if constexpr (MODE != 1) {
#pragma unroll
    for (int r = 0; r < 16; ++r) {
      int ri = w * 32 + (r & 3) + 8 * (r >> 2) + 4 * g;
      x2r[r] = sX2[ri];
      if constexpr (MODE == 2) u2r[r] = sU2[ri];
    }
  }

  float racc[16];
#pragma unroll
  for (int r = 0; r < 16; ++r) racc[r] = 0.f;
  float accS = 0.f;

  // one 128-col quarter: 4 ct steps of 32 cols.
  auto do_quarter = [&](const short* __restrict__ buf, int qq) {
    if constexpr (MODE == 1) {
      // interleaved ct-pairs, dual accumulators (round-6 ILP change)
#pragma unroll
      for (int cp = 0; cp < 2; ++cp) {
        const int ct0 = cp * 2, ct1 = cp * 2 + 1;
        const int nn0 = ct0 * 32 + ln, nn1 = ct1 * 32 + ln;
        s16x8 b0[4], b1[4];
#pragma unroll
        for (int ks = 0; ks < 4; ++ks) {
          const int sw = ((ks * 2 + g) ^ (ln & 7)) * 8;
          b0[ks] = *(const s16x8*)(buf + nn0 * DIM + sw);
          b1[ks] = *(const s16x8*)(buf + nn1 * DIM + sw);
        }
        f32x16 acc0, acc1;
#pragma unroll
        for (int r = 0; r < 16; ++r) { acc0[r] = 0.f; acc1[r] = 0.f; }
#pragma unroll
        for (int ks = 0; ks < 4; ++ks) {
          acc0 = __builtin_amdgcn_mfma_f32_32x32x16_bf16(a_hi[ks], b0[ks], acc0, 0, 0, 0);
          acc1 = __builtin_amdgcn_mfma_f32_32x32x16_bf16(a_hi[ks], b1[ks], acc1, 0, 0, 0);
        }
        const float bb0 = sCol[qq * 128 + ct0 * 32 + ln];
        const float bb1 = sCol[qq * 128 + ct1 * 32 + ln];
        // exp block of ct0 executes while ct1's MFMA chain drains; racc adds
        // stay in ascending-ct order -> bitwise identical to the serial loop.
#pragma unroll
        for (int r = 0; r < 16; ++r)
          racc[r] += exp2_fast(fmaf(C2L, acc0[r], bb0));
#pragma unroll
        for (int r = 0; r < 16; ++r)
          racc[r] += exp2_fast(fmaf(C2L, acc1[r], bb1));
      }
    } else {
#pragma unroll 2
      for (int ct = 0; ct < 4; ++ct) {
        const int nn = ct * 32 + ln;             // row within quarter buffer
        const int n  = qq * 128 + ct * 32 + ln;  // col within 512 panel
        s16x8 b[4];
#pragma unroll
        for (int ks = 0; ks < 4; ++ks)
          b[ks] = *(const s16x8*)(buf + nn * DIM + (((ks * 2 + g) ^ (ln & 7)) * 8));
        f32x16 acc;
#pragma unroll
        for (int r = 0; r < 16; ++r) acc[r] = 0.f;
#pragma unroll
        for (int ks = 0; ks < 4; ++ks)
          acc = __builtin_amdgcn_mfma_f32_32x32x16_bf16(a_hi[ks], b[ks], acc, 0, 0, 0);

        if constexpr (MODE == 0) {
          const float y2v = sY2[n];
#pragma unroll
          for (int r = 0; r < 16; ++r)
            accS = fmaxf(accS, fmaf(-2.0f, acc[r], x2r[r] + y2v));
        } else {
          f32x16 acc2;
#pragma unroll
          for (int r = 0; r < 16; ++r) acc2[r] = 0.f;
#pragma unroll
          for (int ks = 0; ks < 4; ++ks)
            acc2 = __builtin_amdgcn_mfma_f32_32x32x16_bf16(a_lo[ks], b[ks], acc2, 0, 0, 0);
          const float y2v = sY2[n];
          const float bb  = sCol[n];
#pragma unroll
          for (int r = 0; r < 16; ++r) {
            float dot = acc[r] + acc2[r];
            float d2  = fmaxf(fmaf(-2.0f, dot, x2r[r] + y2v), 0.0f);
            accS = fmaf(d2, exp2_fast(fmaf(C2L, dot, u2r[r] + bb)), accS);
          }
        }
      }
    }
  };

  do_quarter(sB[0], 0);
  __syncthreads();               // all waves done reading b0
  stage(2, 0);                   // restage b0; lands under q1 compute
  do_quarter(sB[1], 1);
  __syncthreads();               // drains stage(2) + all reads of b1
  stage(3, 1);                   // restage b1; lands under q2 compute
  do_quarter(sB[0], 2);
  __syncthreads();               // drains stage(3)
  do_quarter(sB[1], 3);

  if constexpr (MODE == 1) {
    // reduce each acc row over its 32 cols (stays within the g-half), store
#pragma unroll
    for (int r = 0; r < 16; ++r) {
      float v = racc[r];
      v += __shfl_xor(v, 1, 64);
      v += __shfl_xor(v, 2, 64);
      v += __shfl_xor(v, 4, 64);
      v += __shfl_xor(v, 8, 64);
      v += __shfl_xor(v, 16, 64);
      if (ln == 0)
        outPart[blockIdx.y * NPTS + i0 + w * 32 +
                (r & 3) + 8 * (r >> 2) + 4 * g] = v;
    }
  } else {
    float v = accS;
#pragma unroll
    for (int off = 1; off < 64; off <<= 1) {
      float o = __shfl_xor(v, off, 64);
      v = (MODE == 0) ? fmaxf(v, o) : (v + o);
    }
    if (l == 0) sRed[w] = v;
    __syncthreads();
    if (t == 0) {
      float r0 = (MODE == 0) ? fmaxf(fmaxf(sRed[0], sRed[1]), fmaxf(sRed[2], sRed[3]))
                             : (sRed[0] + sRed[1] + sRed[2] + sRed[3]);
      if constexpr (MODE == 0)
        atomicMax((unsigned*)outScalar, __float_as_uint(r0));
      else
        atomicAdd(outScalar, r0);
    }
  }
}

// ---------------------------------------------------------------------------
extern "C" void kernel_launch(void* const* d_in, const int* in_sizes, int n_in,
                              void* d_out, int out_size, void* d_ws, size_t ws_size,
                              hipStream_t stream) {
  (void)in_sizes; (void)n_in; (void)out_size; (void)ws_size;
  const float* XP = (const float*)d_in[0];
  const float* XQ = (const float*)d_in[1];
  float* out = (float*)d_out;

  float* ws    = (float*)d_ws;
  float* x2    = ws;                        // 8192
  float* y2    = ws + 8192;                 // 8192
  float* partU = ws + 16384;                // 16 x 8192 (u-pass row sums)
  float* partV = partU + 16 * NPTS;         // 16 x 8192 (v-pass row sums)
  float* scal  = partV + 16 * NPTS;         // [0] = cmax bits (16 reserved)
  unsigned short* Phi = (unsigned short*)(scal + 16);
  unsigned short* Plo = Phi + (size_t)NPTS * DIM;
  unsigned short* Qhi = Plo + (size_t)NPTS * DIM;
  unsigned short* Qlo = Qhi + (size_t)NPTS * DIM;   // total ws ~5.3 MB

  const unsigned* cmaxB = (const unsigned*)scal;
  dim3 grid(NPTS / 128, NPTS / 512);        // (64, 16) = 1024 blocks

  prep_kernel<<<NPTS * 2 * DIM / 256, 256, 0, stream>>>(
      XP, XQ, Phi, Plo, Qhi, Qlo, x2, y2, scal, out);

  // Cmax (hi-only: |err| ~1e-4 relative, shifts effective reg negligibly)
  pass_kernel<0, false, 4><<<grid, 256, 0, stream>>>(
      Phi, nullptr, Qhi, x2, y2, nullptr, nullptr, cmaxB, nullptr, scal);

  // iter 1: u-pass with v = 0 (base from y2), then v-pass from partU
  pass_kernel<1, true, 4><<<grid, 256, 0, stream>>>(
      Phi, nullptr, Qhi, nullptr, y2, nullptr, nullptr, cmaxB, partU, nullptr);
  pass_kernel<1, false, 4><<<grid, 256, 0, stream>>>(
      Qhi, nullptr, Phi, nullptr, nullptr, partU, nullptr, cmaxB, partV, nullptr);

  for (int it = 1; it < 20; ++it) {
    pass_kernel<1, false, 4><<<grid, 256, 0, stream>>>(
        Phi, nullptr, Qhi, nullptr, nullptr, partV, nullptr, cmaxB, partU, nullptr);
    pass_kernel<1, false, 4><<<grid, 256, 0, stream>>>(
        Qhi, nullptr, Phi, nullptr, nullptr, partU, nullptr, cmaxB, partV, nullptr);
  }

  // final: sum C * plan (hi+lo dot for C accuracy)
  pass_kernel<2, false, 2><<<grid, 256, 0, stream>>>(
      Phi, Plo, Qhi, x2, y2, partV, partU, cmaxB, nullptr, out);
}

// Round 7
// 817.494 us; speedup vs baseline: 25.4906x; 25.4906x over previous
//
#include <hip/hip_runtime.h>
#include <cmath>

// n = m = 8192, d = 64, reg = 0.05, 20 Sinkhorn iterations
#define NPTS 8192
#define DIM  64
#define LOG2E 1.4426950408889634f
#define LA2   -13.0f   // log2(1/8192) exactly
#define NSWEEP 40      // MODE-1 sweeps (1 first-u + 1 first-v + 19*2)

typedef short s16x8  __attribute__((ext_vector_type(8)));   // 8 bf16
typedef float f32x16 __attribute__((ext_vector_type(16)));  // MFMA 32x32 acc

typedef __attribute__((address_space(1))) const unsigned char g8_t;
typedef __attribute__((address_space(3))) unsigned char l8_t;

#if __has_builtin(__builtin_amdgcn_exp2f)
__device__ __forceinline__ float exp2_fast(float x) { return __builtin_amdgcn_exp2f(x); }
#else
__device__ __forceinline__ float exp2_fast(float x) { return exp2f(x); }
#endif
#if __has_builtin(__builtin_amdgcn_logf)
__device__ __forceinline__ float log2_fast(float x) { return __builtin_amdgcn_logf(x); }
#else
__device__ __forceinline__ float log2_fast(float x) { return log2f(x); }
#endif

__device__ __forceinline__ unsigned short f2bf(float x) {
  unsigned u = __float_as_uint(x);
  return (unsigned short)((u + 0x7FFFu + ((u >> 16) & 1u)) >> 16);
}
__device__ __forceinline__ float bf2f(unsigned short b) {
  return __uint_as_float(((unsigned)b) << 16);
}

// ---------------------------------------------------------------------------
// prep: bf16 hi/lo split + squared row norms; zero all per-sweep partial
// regions (40 x 8192 floats) + scal/out. one wave per row.
// ---------------------------------------------------------------------------
__global__ __launch_bounds__(256) void prep_kernel(
    const float* __restrict__ XP, const float* __restrict__ XQ,
    unsigned short* __restrict__ Phi, unsigned short* __restrict__ Plo,
    unsigned short* __restrict__ Qhi, unsigned short* __restrict__ Qlo,
    float* __restrict__ x2, float* __restrict__ y2,
    float* __restrict__ partS,
    float* __restrict__ scal, float* __restrict__ out) {
  int gid  = blockIdx.x * 256 + threadIdx.x;
  int lane = threadIdx.x & 63;
  int row  = gid >> 6;            // 0..16383: P rows then Q rows (wave-uniform)
  int isP  = row < NPTS;
  int r    = row & (NPTS - 1);
  const float* X = isP ? XP : XQ;
  float x = X[r * DIM + lane];
  unsigned short h = f2bf(x);
  (isP ? Phi : Qhi)[r * DIM + lane] = h;
  (isP ? Plo : Qlo)[r * DIM + lane] = f2bf(x - bf2f(h));
  float s = x * x;
  for (int off = 32; off; off >>= 1) s += __shfl_down(s, off, 64);
  if (lane == 0) (isP ? x2 : y2)[r] = s;
  if (gid < NSWEEP * NPTS) partS[gid] = 0.0f;   // zero atomic-partial regions
  if (gid == 0) { ((unsigned*)scal)[0] = 0u; out[0] = 0.0f; }
}

// ---------------------------------------------------------------------------
// pass_kernel<MODE, FIRST, MINW>: one (128 rows x 512 cols) tile sweep.
// Verified r2 structure (820 us, absmax 0): B staged via global_load_lds as
// FOUR 16 KB quarters, double-buffered in sB[2]; 3 mid-sweep barriers;
// serial ct loop (fits the de-facto 64-VGPR budget -- r6 proved exceeding it
// spills to scratch at 1.7 GB/dispatch).
// Round-7 change: SINGLE-ARRAY ATOMIC PARTIALS. MODE-1 producers atomicAdd
// each row's 512-col partial into colPart-region[i] (16 atomics/wave, same
// count as the stores they replace); consumers read ONE float per column
// (512 loads/block instead of 8192) + one log2. Regions are pre-zeroed in
// prep; cross-sweep visibility via kernel boundary (already relied on).
// MODE 0: cmax = max d2 (hi dot)                 -> atomicMax(uint) outScalar
// MODE 1: row sums of 2^(C2L*dot + b_j)          -> atomicAdd outPart[i]
// MODE 2: out += d2 * 2^(C2L*dot + bu_i + bv_j)  -> atomicAdd outScalar
// C/D layout (m74/m101): col = lane&31, row = (reg&3) + 8*(reg>>2) + 4*(lane>>5)
// ---------------------------------------------------------------------------
template <int MODE, bool FIRST, int MINW>
__global__ __launch_bounds__(256, MINW) void pass_kernel(
    const unsigned short* __restrict__ Ahi, const unsigned short* __restrict__ Alo,
    const unsigned short* __restrict__ Bhi,
    const float* __restrict__ x2row, const float* __restrict__ y2col,
    const float* __restrict__ colPart,   // prev-sweep summed partials (cols)
    const float* __restrict__ rowPart,   // prev-sweep summed partials (rows)
    const unsigned* __restrict__ cmaxBits,
    float* __restrict__ outPart, float* __restrict__ outScalar) {
  __shared__ short sB[2][128 * DIM];   // 2 x 16 KB quarter buffers, xor-swizzled
  __shared__ float sCol[512];          // per-col log2-domain base (modes 1,2)
  __shared__ float sY2[512];           // modes 0,2
  __shared__ float sX2[128];           // modes 0,2
  __shared__ float sU2[128];           // mode 2
  __shared__ float sRed[4];

  const int t  = threadIdx.x;
  const int w  = t >> 6;
  const int l  = t & 63;
  const int g  = l >> 5;
  const int ln = l & 31;
  const int i0 = blockIdx.x * 128;
  const int j0 = blockIdx.y * 512;

  float invC = 0.f, C2L = 0.f;
  if constexpr (MODE != 0) {
    float cmax = __uint_as_float(*cmaxBits);
    invC = 1.0f / (0.05f * cmax);
    C2L  = 2.0f * invC * LOG2E;
  }

  // staging geometry (verified r1/r2): slot s = w*256 + c*64 + l holds
  // (row = s>>3, chunk cc = (s&7)^(row&7)); row&7 == l>>3 -> cc c-invariant.
  const int gOff   = (w * 32 + (l >> 3)) * 128 + (((l & 7) ^ (l >> 3)) * 16);
  const int ldsOff = w * 4096 + l * 16;
  auto stage = [&](int qq, int bi) {
    const unsigned char* src =
        (const unsigned char*)(Bhi + (size_t)(j0 + qq * 128) * DIM) + gOff;
    unsigned char* dst = (unsigned char*)(&sB[bi][0]) + ldsOff;
#pragma unroll
    for (int c = 0; c < 4; ++c)
      __builtin_amdgcn_global_load_lds((g8_t*)(src + c * 1024),
                                       (l8_t*)(dst + c * 1024), 16, 0, 0);
  };

  stage(0, 0);
  stage(1, 1);

  // A fragments: lane holds A[m=ln][k = ks*16 + g*8 + j]
  s16x8 a_hi[4], a_lo[4];
  {
    const unsigned short* pa = Ahi + (size_t)(i0 + w * 32 + ln) * DIM + g * 8;
#pragma unroll
    for (int ks = 0; ks < 4; ++ks) a_hi[ks] = *(const s16x8*)(pa + ks * 16);
    if constexpr (MODE == 2) {
      const unsigned short* pb = Alo + (size_t)(i0 + w * 32 + ln) * DIM + g * 8;
#pragma unroll
      for (int ks = 0; ks < 4; ++ks) a_lo[ks] = *(const s16x8*)(pb + ks * 16);
    }
  }

  // whole-panel column bases / norms (overlaps the in-flight staging)
#pragma unroll
  for (int c0 = 0; c0 < 2; ++c0) {
    int c = c0 * 256 + t;
    int j = j0 + c;
    if constexpr (MODE == 0) {
      sY2[c] = y2col[j];
    } else if constexpr (MODE == 1) {
      if constexpr (FIRST) {
        sCol[c] = -invC * y2col[j] * LOG2E;
      } else {
        sCol[c] = LA2 - log2_fast(colPart[j]);   // single pre-summed partial
      }
    } else {
      sCol[c] = LA2 - log2_fast(colPart[j]);
      sY2[c] = y2col[j];
    }
  }
  if constexpr (MODE != 1) {
    if (t < 128) {
      sX2[t] = x2row[i0 + t];
      if constexpr (MODE == 2)
        sU2[t] = LA2 - log2_fast(rowPart[i0 + t]);
    }
  }
  __syncthreads();   // drains quarters 0+1 (vmcnt at barrier), publishes sCol/...

  float x2r[16], u2r[16];
  if constexpr (MODE != 1) {
#pragma unroll
    for (int r = 0; r < 16; ++r) {
      int ri = w * 32 + (r & 3) + 8 * (r >> 2) + 4 * g;
      x2r[r] = sX2[ri];
      if constexpr (MODE == 2) u2r[r] = sU2[ri];
    }
  }

  float racc[16];
#pragma unroll
  for (int r = 0; r < 16; ++r) racc[r] = 0.f;
  float accS = 0.f;

  // one 128-col quarter: 4 ct steps of 32 cols (verified r2 body)
  auto do_quarter = [&](const short* __restrict__ buf, int qq) {
#pragma unroll 2
    for (int ct = 0; ct < 4; ++ct) {
      const int nn = ct * 32 + ln;             // row within quarter buffer
      const int n  = qq * 128 + ct * 32 + ln;  // col within 512 panel
      s16x8 b[4];
#pragma unroll
      for (int ks = 0; ks < 4; ++ks)
        b[ks] = *(const s16x8*)(buf + nn * DIM + (((ks * 2 + g) ^ (ln & 7)) * 8));
      f32x16 acc;
#pragma unroll
      for (int r = 0; r < 16; ++r) acc[r] = 0.f;
#pragma unroll
      for (int ks = 0; ks < 4; ++ks)
        acc = __builtin_amdgcn_mfma_f32_32x32x16_bf16(a_hi[ks], b[ks], acc, 0, 0, 0);

      if constexpr (MODE == 1) {
        const float bb = sCol[n];
#pragma unroll
        for (int r = 0; r < 16; ++r)
          racc[r] += exp2_fast(fmaf(C2L, acc[r], bb));
      } else if constexpr (MODE == 0) {
        const float y2v = sY2[n];
#pragma unroll
        for (int r = 0; r < 16; ++r)
          accS = fmaxf(accS, fmaf(-2.0f, acc[r], x2r[r] + y2v));
      } else {
        f32x16 acc2;
#pragma unroll
        for (int r = 0; r < 16; ++r) acc2[r] = 0.f;
#pragma unroll
        for (int ks = 0; ks < 4; ++ks)
          acc2 = __builtin_amdgcn_mfma_f32_32x32x16_bf16(a_lo[ks], b[ks], acc2, 0, 0, 0);
        const float y2v = sY2[n];
        const float bb  = sCol[n];
#pragma unroll
        for (int r = 0; r < 16; ++r) {
          float dot = acc[r] + acc2[r];
          float d2  = fmaxf(fmaf(-2.0f, dot, x2r[r] + y2v), 0.0f);
          accS = fmaf(d2, exp2_fast(fmaf(C2L, dot, u2r[r] + bb)), accS);
        }
      }
    }
  };

  do_quarter(sB[0], 0);
  __syncthreads();               // all waves done reading b0
  stage(2, 0);                   // restage b0; lands under q1 compute
  do_quarter(sB[1], 1);
  __syncthreads();               // drains stage(2) + all reads of b1
  stage(3, 1);                   // restage b1; lands under q2 compute
  do_quarter(sB[0], 2);
  __syncthreads();               // drains stage(3)
  do_quarter(sB[1], 3);

  if constexpr (MODE == 1) {
    // reduce each acc row over its 32 cols, then atomically accumulate the
    // 512-col partial into the sweep's region (replaces the 16-slice store)
#pragma unroll
    for (int r = 0; r < 16; ++r) {
      float v = racc[r];
      v += __shfl_xor(v, 1, 64);
      v += __shfl_xor(v, 2, 64);
      v += __shfl_xor(v, 4, 64);
      v += __shfl_xor(v, 8, 64);
      v += __shfl_xor(v, 16, 64);
      if (ln == 0)
        atomicAdd(&outPart[i0 + w * 32 + (r & 3) + 8 * (r >> 2) + 4 * g], v);
    }
  } else {
    float v = accS;
#pragma unroll
    for (int off = 1; off < 64; off <<= 1) {
      float o = __shfl_xor(v, off, 64);
      v = (MODE == 0) ? fmaxf(v, o) : (v + o);
    }
    if (l == 0) sRed[w] = v;
    __syncthreads();
    if (t == 0) {
      float r0 = (MODE == 0) ? fmaxf(fmaxf(sRed[0], sRed[1]), fmaxf(sRed[2], sRed[3]))
                             : (sRed[0] + sRed[1] + sRed[2] + sRed[3]);
      if constexpr (MODE == 0)
        atomicMax((unsigned*)outScalar, __float_as_uint(r0));
      else
        atomicAdd(outScalar, r0);
    }
  }
}

// ---------------------------------------------------------------------------
extern "C" void kernel_launch(void* const* d_in, const int* in_sizes, int n_in,
                              void* d_out, int out_size, void* d_ws, size_t ws_size,
                              hipStream_t stream) {
  (void)in_sizes; (void)n_in; (void)out_size; (void)ws_size;
  const float* XP = (const float*)d_in[0];
  const float* XQ = (const float*)d_in[1];
  float* out = (float*)d_out;

  float* ws    = (float*)d_ws;
  float* x2    = ws;                        // 8192
  float* y2    = ws + 8192;                 // 8192
  float* partS = ws + 16384;                // 40 x 8192 per-sweep partials
  float* scal  = partS + NSWEEP * NPTS;     // [0] = cmax bits (16 reserved)
  unsigned short* Phi = (unsigned short*)(scal + 16);
  unsigned short* Plo = Phi + (size_t)NPTS * DIM;
  unsigned short* Qhi = Plo + (size_t)NPTS * DIM;
  unsigned short* Qlo = Qhi + (size_t)NPTS * DIM;   // total ws ~5.6 MB

  const unsigned* cmaxB = (const unsigned*)scal;
  dim3 grid(NPTS / 128, NPTS / 512);        // (64, 16) = 1024 blocks

  prep_kernel<<<NPTS * 2 * DIM / 256, 256, 0, stream>>>(
      XP, XQ, Phi, Plo, Qhi, Qlo, x2, y2, partS, scal, out);

  // Cmax (hi-only: |err| ~1e-4 relative, shifts effective reg negligibly)
  pass_kernel<0, false, 4><<<grid, 256, 0, stream>>>(
      Phi, nullptr, Qhi, x2, y2, nullptr, nullptr, cmaxB, nullptr, scal);

  // sweep s writes region s; sweep s+1 reads region s (kernel-boundary sync)
  auto reg = [&](int s) { return partS + (size_t)s * NPTS; };

  // s=0: u-pass with v = 0 (base from y2); s=1: first v-pass
  pass_kernel<1, true, 4><<<grid, 256, 0, stream>>>(
      Phi, nullptr, Qhi, nullptr, y2, nullptr, nullptr, cmaxB, reg(0), nullptr);
  pass_kernel<1, false, 4><<<grid, 256, 0, stream>>>(
      Qhi, nullptr, Phi, nullptr, nullptr, reg(0), nullptr, cmaxB, reg(1), nullptr);

  for (int it = 1; it < 20; ++it) {
    int s = it * 2;
    pass_kernel<1, false, 4><<<grid, 256, 0, stream>>>(
        Phi, nullptr, Qhi, nullptr, nullptr, reg(s - 1), nullptr, cmaxB, reg(s), nullptr);
    pass_kernel<1, false, 4><<<grid, 256, 0, stream>>>(
        Qhi, nullptr, Phi, nullptr, nullptr, reg(s), nullptr, cmaxB, reg(s + 1), nullptr);
  }

  // final: sum C * plan (hi+lo dot for C accuracy); rows from last u-pass
  // (region 38), cols from last v-pass (region 39)
  pass_kernel<2, false, 2><<<grid, 256, 0, stream>>>(
      Phi, Plo, Qhi, x2, y2, reg(39), reg(38), cmaxB, nullptr, out);
}